// Round 1
// baseline (14178.075 us; speedup 1.0000x reference)
//
#include <hip/hip_runtime.h>
#include <cstdint>
#include <cstddef>

#define SEQ 4096
#define HID 512
#define NTHETA 5
#define NWORK 8

__device__ __forceinline__ float tanh_fast(float x) {
  x = fminf(fmaxf(x, -20.0f), 20.0f);
  const float e = __expf(2.0f * x);
  return (e - 1.0f) / (e + 1.0f);
}

// C[4096,512] = act(A[4096,K] @ W[512,K]^T + bias + noise_plane)
__global__ __launch_bounds__(256) void gemm_bias_noise(
    const float* __restrict__ A, const float* __restrict__ W,
    const float* __restrict__ bias, const float* __restrict__ noise,
    float* __restrict__ C, int K, int doTanh)
{
  const int N = HID;
  const int bm = blockIdx.y, bn = blockIdx.x;
  const int tid = threadIdx.x;
  const int tx = tid & 15, ty = tid >> 4;
  const int row0 = bm * 64, col0 = bn * 64;
  __shared__ float As[16][68];
  __shared__ float Ws[16][68];
  float acc[4][4] = {{0.f, 0.f, 0.f, 0.f}, {0.f, 0.f, 0.f, 0.f},
                     {0.f, 0.f, 0.f, 0.f}, {0.f, 0.f, 0.f, 0.f}};
  const int lrow = tid >> 2, lkq = tid & 3;
  for (int kt = 0; kt < K; kt += 16) {
    const float4 av = *(const float4*)&A[(size_t)(row0 + lrow) * K + kt + lkq * 4];
    const float4 wv = *(const float4*)&W[(size_t)(col0 + lrow) * K + kt + lkq * 4];
    __syncthreads();
    As[lkq * 4 + 0][lrow] = av.x; As[lkq * 4 + 1][lrow] = av.y;
    As[lkq * 4 + 2][lrow] = av.z; As[lkq * 4 + 3][lrow] = av.w;
    Ws[lkq * 4 + 0][lrow] = wv.x; Ws[lkq * 4 + 1][lrow] = wv.y;
    Ws[lkq * 4 + 2][lrow] = wv.z; Ws[lkq * 4 + 3][lrow] = wv.w;
    __syncthreads();
#pragma unroll
    for (int k = 0; k < 16; ++k) {
      const float4 a = *(const float4*)&As[k][ty * 4];
      const float4 bq = *(const float4*)&Ws[k][tx * 4];
      const float a4[4] = {a.x, a.y, a.z, a.w};
      const float b4[4] = {bq.x, bq.y, bq.z, bq.w};
#pragma unroll
      for (int i = 0; i < 4; ++i)
#pragma unroll
        for (int j = 0; j < 4; ++j)
          acc[i][j] = fmaf(a4[i], b4[j], acc[i][j]);
    }
  }
  const float4 bv = *(const float4*)&bias[col0 + tx * 4];
#pragma unroll
  for (int i = 0; i < 4; ++i) {
    const int row = row0 + ty * 4 + i;
    const float4 nv = *(const float4*)&noise[(size_t)row * N + col0 + tx * 4];
    float4 o;
    o.x = acc[i][0] + bv.x + nv.x;
    o.y = acc[i][1] + bv.y + nv.y;
    o.z = acc[i][2] + bv.z + nv.z;
    o.w = acc[i][3] + bv.w + nv.w;
    if (doTanh) {
      o.x = tanh_fast(o.x); o.y = tanh_fast(o.y);
      o.z = tanh_fast(o.z); o.w = tanh_fast(o.w);
    }
    *(float4*)&C[(size_t)row * N + col0 + tx * 4] = o;
  }
}

// Sequential scan: h_t = tanh(drive_t + W_hh @ h_{t-1}), hs written to out0.
// 8 blocks, each owns 64 output rows; W slice lives in registers.
__global__ __launch_bounds__(1024) void recurrence(
    const float* __restrict__ Whh, const float* __restrict__ drive,
    const float* __restrict__ h0, float* __restrict__ out0,
    int* __restrict__ flags)
{
  const int blk = blockIdx.x;          // 0..7
  const int base = blk * 64;
  const int tid = threadIdx.x;
  const int r = tid >> 4;              // 0..63  (local output row)
  const int s = tid & 15;              // 0..15  (j-slice)
  __shared__ float hsh[512];
  __shared__ float ysh[64];

  float w[32];
  {
    const float* wrow = &Whh[(size_t)(base + r) * 512 + s * 32];
#pragma unroll
    for (int q = 0; q < 8; ++q) {
      const float4 v = *(const float4*)&wrow[q * 4];
      w[q * 4 + 0] = v.x; w[q * 4 + 1] = v.y;
      w[q * 4 + 2] = v.z; w[q * 4 + 3] = v.w;
    }
  }

  for (int t = 0; t < SEQ; ++t) {
    if (t > 0) {
      if (tid == 0) {
        while (__hip_atomic_load(&flags[t - 1], __ATOMIC_RELAXED,
                                 __HIP_MEMORY_SCOPE_AGENT) < NWORK) { }
        __builtin_amdgcn_fence(__ATOMIC_ACQUIRE, "agent");
      }
      __syncthreads();                                   // (A)
    }
    const float* hsrc = (t == 0) ? h0 : &out0[(size_t)(t - 1) * HID];
    float4 hv;
    if (tid < 128) hv = *(const float4*)&hsrc[tid * 4];
    float drv = 0.f;
    if (tid < 64) drv = drive[(size_t)t * HID + base + tid];
    if (tid < 128) *(float4*)&hsh[tid * 4] = hv;
    __syncthreads();                                     // (B)

    float sum = 0.f;
#pragma unroll
    for (int q = 0; q < 8; ++q) {
      const float4 h4 = *(const float4*)&hsh[s * 32 + q * 4];
      sum = fmaf(w[q * 4 + 0], h4.x, sum);
      sum = fmaf(w[q * 4 + 1], h4.y, sum);
      sum = fmaf(w[q * 4 + 2], h4.z, sum);
      sum = fmaf(w[q * 4 + 3], h4.w, sum);
    }
#pragma unroll
    for (int off = 1; off < 16; off <<= 1)
      sum += __shfl_xor(sum, off, 64);
    if (s == 0) ysh[r] = sum;
    __syncthreads();                                     // (C)

    if (tid < 64) {
      const float y = tanh_fast(ysh[tid] + drv);
      out0[(size_t)t * HID + base + tid] = y;
      if (tid == 0) {
        __builtin_amdgcn_fence(__ATOMIC_RELEASE, "agent");
        __hip_atomic_fetch_add(&flags[t], 1, __ATOMIC_RELAXED,
                               __HIP_MEMORY_SCOPE_AGENT);
      }
    }
  }
}

__global__ void copy_final(const float* __restrict__ src, float* __restrict__ dst) {
  dst[threadIdx.x] = src[threadIdx.x];
}

extern "C" void kernel_launch(void* const* d_in, const int* in_sizes, int n_in,
                              void* d_out, int out_size, void* d_ws, size_t ws_size,
                              hipStream_t stream) {
  const float* input    = (const float*)d_in[0];
  const float* internal = (const float*)d_in[1];
  const float* state    = (const float*)d_in[2];
  const float* W_ih     = (const float*)d_in[3];
  const float* W_hh     = (const float*)d_in[4];
  const float* bias     = (const float*)d_in[5];
  float* out = (float*)d_out;

  int* flags = (int*)d_ws;
  const size_t plane = (size_t)SEQ * HID;
  const size_t need = 16 * 1024 + plane * sizeof(float);
  float* drive = (ws_size >= need) ? (float*)((char*)d_ws + 16 * 1024)
                                   : out + 5 * plane;  // plane 5 written last

  hipMemsetAsync(d_ws, 0, SEQ * sizeof(int), stream);

  dim3 gg(HID / 64, SEQ / 64);
  // drive = x @ W_ih^T + b + internal[0]   (no tanh)
  gemm_bias_noise<<<gg, 256, 0, stream>>>(input, W_ih, bias, internal, drive,
                                          HID, 0);
  // hs (out plane 0)
  recurrence<<<NWORK, 1024, 0, stream>>>(W_hh, drive, state, out, flags);
  // theta rollouts: plane k -> plane k+1
  for (int k = 0; k < NTHETA; ++k) {
    gemm_bias_noise<<<gg, 256, 0, stream>>>(out + (size_t)k * plane, W_hh, bias,
                                            internal + (size_t)(k + 1) * plane,
                                            out + (size_t)(k + 1) * plane,
                                            HID, 1);
  }
  // final_state = hs[4095]
  copy_final<<<1, HID, 0, stream>>>(out + (size_t)4095 * HID, out + 6 * plane);
}

// Round 2
// 7165.992 us; speedup vs baseline: 1.9785x; 1.9785x over previous
//
#include <hip/hip_runtime.h>
#include <cstdint>
#include <cstddef>

#define SEQ 4096
#define HID 512
#define NTHETA 5
#define NBLK 8
#define SENT_BITS 0x40000000u   // 2.0f — |tanh| < 1, so never a real h value

__device__ __forceinline__ float tanh_fast(float x) {
  x = fminf(fmaxf(x, -20.0f), 20.0f);
  const float e = __expf(2.0f * x);
  return (e - 1.0f) / (e + 1.0f);
}

// C[4096,512] = act(A[4096,K] @ W[512,K]^T + bias + noise_plane)
__global__ __launch_bounds__(256) void gemm_bias_noise(
    const float* __restrict__ A, const float* __restrict__ W,
    const float* __restrict__ bias, const float* __restrict__ noise,
    float* __restrict__ C, int K, int doTanh)
{
  const int N = HID;
  const int bm = blockIdx.y, bn = blockIdx.x;
  const int tid = threadIdx.x;
  const int tx = tid & 15, ty = tid >> 4;
  const int row0 = bm * 64, col0 = bn * 64;
  __shared__ float As[16][68];
  __shared__ float Ws[16][68];
  float acc[4][4] = {{0.f, 0.f, 0.f, 0.f}, {0.f, 0.f, 0.f, 0.f},
                     {0.f, 0.f, 0.f, 0.f}, {0.f, 0.f, 0.f, 0.f}};
  const int lrow = tid >> 2, lkq = tid & 3;
  for (int kt = 0; kt < K; kt += 16) {
    const float4 av = *(const float4*)&A[(size_t)(row0 + lrow) * K + kt + lkq * 4];
    const float4 wv = *(const float4*)&W[(size_t)(col0 + lrow) * K + kt + lkq * 4];
    __syncthreads();
    As[lkq * 4 + 0][lrow] = av.x; As[lkq * 4 + 1][lrow] = av.y;
    As[lkq * 4 + 2][lrow] = av.z; As[lkq * 4 + 3][lrow] = av.w;
    Ws[lkq * 4 + 0][lrow] = wv.x; Ws[lkq * 4 + 1][lrow] = wv.y;
    Ws[lkq * 4 + 2][lrow] = wv.z; Ws[lkq * 4 + 3][lrow] = wv.w;
    __syncthreads();
#pragma unroll
    for (int k = 0; k < 16; ++k) {
      const float4 a = *(const float4*)&As[k][ty * 4];
      const float4 bq = *(const float4*)&Ws[k][tx * 4];
      const float a4[4] = {a.x, a.y, a.z, a.w};
      const float b4[4] = {bq.x, bq.y, bq.z, bq.w};
#pragma unroll
      for (int i = 0; i < 4; ++i)
#pragma unroll
        for (int j = 0; j < 4; ++j)
          acc[i][j] = fmaf(a4[i], b4[j], acc[i][j]);
    }
  }
  const float4 bv = *(const float4*)&bias[col0 + tx * 4];
#pragma unroll
  for (int i = 0; i < 4; ++i) {
    const int row = row0 + ty * 4 + i;
    const float4 nv = *(const float4*)&noise[(size_t)row * N + col0 + tx * 4];
    float4 o;
    o.x = acc[i][0] + bv.x + nv.x;
    o.y = acc[i][1] + bv.y + nv.y;
    o.z = acc[i][2] + bv.z + nv.z;
    o.w = acc[i][3] + bv.w + nv.w;
    if (doTanh) {
      o.x = tanh_fast(o.x); o.y = tanh_fast(o.y);
      o.z = tanh_fast(o.z); o.w = tanh_fast(o.w);
    }
    *(float4*)&C[(size_t)row * N + col0 + tx * 4] = o;
  }
}

// Pre-fill the h-exchange buffer with the sentinel (2.0f bit pattern).
__global__ void fill_sentinel(uint4* __restrict__ p, int n4) {
  const int i = blockIdx.x * blockDim.x + threadIdx.x;
  if (i < n4) p[i] = make_uint4(SENT_BITS, SENT_BITS, SENT_BITS, SENT_BITS);
}

// f4-granular XOR swizzle: permutes the 8 float4 slots within each 8-slot row.
__device__ __forceinline__ int swz_f4(int j) {
  return (j & ~7) | ((j & 7) ^ ((j >> 3) & 7));
}

// Sequential scan: h_t = tanh(drive_t + W_hh @ h_{t-1}).
// 8 blocks × 1024 thr; block owns 64 rows, W slice in registers.
// Cross-block exchange: sentinel-polled relaxed agent atomics (1 L3 trip/step).
__global__ __launch_bounds__(1024) void recurrence(
    const float* __restrict__ Whh, const float* __restrict__ drive,
    const float* __restrict__ h0, float* __restrict__ out0,
    unsigned* __restrict__ hexch)
{
  const int base = blockIdx.x * 64;   // this block's 64 output rows
  const int tid = threadIdx.x;
  const int r = tid >> 4;             // local output row 0..63
  const int s = tid & 15;             // 16-lane col-slice 0..15
  __shared__ float4 hsh4[128];        // swizzled h (512 floats)
  __shared__ float ysh[64];
  float* hshf = (float*)hsh4;

  // W slice -> registers: row (base+r), cols s*32 .. s*32+31
  float w[32];
  {
    const float* wrow = &Whh[(size_t)(base + r) * HID + s * 32];
#pragma unroll
    for (int q = 0; q < 8; ++q) {
      const float4 v = *(const float4*)&wrow[q * 4];
      w[q * 4 + 0] = v.x; w[q * 4 + 1] = v.y;
      w[q * 4 + 2] = v.z; w[q * 4 + 3] = v.w;
    }
  }

  // swizzled scalar write index for element tid
  int widx = 0;
  if (tid < HID) {
    const int j = tid >> 2, c = tid & 3;
    widx = swz_f4(j) * 4 + c;
  }

  for (int t = 0; t < SEQ; ++t) {
    float drv = 0.f;
    if (tid < 64) drv = drive[(size_t)t * HID + base + tid];  // independent load

    if (tid < HID) {
      float v;
      if (t == 0) {
        v = h0[tid];
      } else {
        const unsigned* src = &hexch[(size_t)(t - 1) * HID + tid];
        unsigned u = __hip_atomic_load(src, __ATOMIC_RELAXED,
                                       __HIP_MEMORY_SCOPE_AGENT);
        while (__any(u == SENT_BITS)) {
          u = __hip_atomic_load(src, __ATOMIC_RELAXED,
                                __HIP_MEMORY_SCOPE_AGENT);
        }
        v = __uint_as_float(u);
      }
      hshf[widx] = v;
    }
    __syncthreads();                                  // (B) hsh ready

    float sum = 0.f;
#pragma unroll
    for (int q = 0; q < 8; ++q) {
      // slot s*8 + (q ^ (s&7)) holds original f4 (s,q) -> pairs with w[q*4..]
      const float4 h4 = hsh4[s * 8 + (q ^ (s & 7))];
      sum = fmaf(w[q * 4 + 0], h4.x, sum);
      sum = fmaf(w[q * 4 + 1], h4.y, sum);
      sum = fmaf(w[q * 4 + 2], h4.z, sum);
      sum = fmaf(w[q * 4 + 3], h4.w, sum);
    }
#pragma unroll
    for (int off = 1; off < 16; off <<= 1)
      sum += __shfl_xor(sum, off, 64);
    if (s == 0) ysh[r] = sum;
    __syncthreads();                                  // (C) ysh ready; also
                                                      // protects hsh4 reuse
    if (tid < 64) {
      const float y = tanh_fast(ysh[tid] + drv);
      out0[(size_t)t * HID + base + tid] = y;          // plain (read next kernel)
      __hip_atomic_store(&hexch[(size_t)t * HID + base + tid],
                         __float_as_uint(y), __ATOMIC_RELAXED,
                         __HIP_MEMORY_SCOPE_AGENT);    // coherent-point store
    }
    // no barrier: next-step hsh writes are gated by the poll, which needs
    // this block's wave-0 stores; cross-wave hsh reuse is protected by (C).
  }
}

__global__ void copy_final(const float* __restrict__ src, float* __restrict__ dst) {
  dst[threadIdx.x] = src[threadIdx.x];
}

extern "C" void kernel_launch(void* const* d_in, const int* in_sizes, int n_in,
                              void* d_out, int out_size, void* d_ws, size_t ws_size,
                              hipStream_t stream) {
  const float* input    = (const float*)d_in[0];
  const float* internal = (const float*)d_in[1];
  const float* state    = (const float*)d_in[2];
  const float* W_ih     = (const float*)d_in[3];
  const float* W_hh     = (const float*)d_in[4];
  const float* bias     = (const float*)d_in[5];
  float* out = (float*)d_out;

  const size_t plane = (size_t)SEQ * HID;
  // Scratch inside d_out (stream-ordered overwrites make this safe):
  //   hexch  = plane 4 (rewritten by theta-GEMM k=3 afterwards)
  //   drive  = plane 5 (rewritten by theta-GEMM k=4 afterwards)
  unsigned* hexch = (unsigned*)(out + 4 * plane);
  float*    drive = out + 5 * plane;

  fill_sentinel<<<(SEQ * HID / 4 + 255) / 256, 256, 0, stream>>>(
      (uint4*)hexch, SEQ * HID / 4);

  dim3 gg(HID / 64, SEQ / 64);
  // drive = x @ W_ih^T + b + internal[0]   (no tanh)
  gemm_bias_noise<<<gg, 256, 0, stream>>>(input, W_ih, bias, internal, drive,
                                          HID, 0);
  // hs (out plane 0)
  recurrence<<<NBLK, 1024, 0, stream>>>(W_hh, drive, state, out, hexch);
  // theta rollouts: plane k -> plane k+1
  for (int k = 0; k < NTHETA; ++k) {
    gemm_bias_noise<<<gg, 256, 0, stream>>>(out + (size_t)k * plane, W_hh, bias,
                                            internal + (size_t)(k + 1) * plane,
                                            out + (size_t)(k + 1) * plane,
                                            HID, 1);
  }
  // final_state = hs[4095]
  copy_final<<<1, HID, 0, stream>>>(out + (size_t)4095 * HID, out + 6 * plane);
}